// Round 10
// baseline (373.480 us; speedup 1.0000x reference)
//
#include <hip/hip_runtime.h>
#include <math.h>

// VQVAE graph-transformer forward, fp32 throughout.
// B=4 N=128 DIM=256 HEADS=8 DH=64 EDGE=64 DEPTH=2 K=512 INNER=512
// R10 = R8 (best passing: 365.8us) +
//  - attn head-paired: 512 blocks x 256 thr; two (b,h,iq) units per block in
//    thread halves sharing (b,iq) -> identical e/eT addresses, L1/L2 coalesce
//    (halves R8's ~270MB/layer of L3 e-traffic).
//  - finer split-K: exp z=4, ff1 z=4, ff2 z=8; consumers sum N partials.
// Cooperative mega-kernel abandoned: hipLaunchCooperativeKernel breaks the
// harness's graph capture (R9 failure).

#define DEV __device__ __forceinline__

constexpr int Bn = 4, Nn = 128, DIMn = 256, HEADSn = 8, DHn = 64, EDGEn = 64,
              DEPTHn = 2, Kn = 512, INNERn = 512;
constexpr int QKVW = 1536;
constexpr int PART = 131072;  // stride of proj partial buffers (floats)

DEV float wave_reduce_sum(float v) {
#pragma unroll
  for (int m = 32; m >= 1; m >>= 1) v += __shfl_xor(v, m);
  return v;
}

DEV float block_reduce_sum_256(float v, float* red) {
  v = wave_reduce_sum(v);
  int tid = threadIdx.x;
  if ((tid & 63) == 0) red[tid >> 6] = v;
  __syncthreads();
  v = red[0] + red[1] + red[2] + red[3];
  __syncthreads();
  return v;
}

DEV float gelu_exact(float x) {
  return 0.5f * x * (1.f + erff(x * 0.70710678118654752f));
}

// ---------------------------------------------------------------------------
// prep_kernel: all one-shot setup, block-range dispatched. 256 threads.
//  blk 0..63: wfold W2; 64..71: wfold bias; 72..583: edge LN; 584..599: rope;
//  600..1111: LN0 row + nodes copy.
__global__ __launch_bounds__(256) void prep_kernel(
    const float* __restrict__ edges, const float* __restrict__ eg,
    const float* __restrict__ ebb, float* __restrict__ e,
    float* __restrict__ eT, float* __restrict__ cost, float* __restrict__ sint,
    const float* __restrict__ nodes_in, const float* __restrict__ ln1_g,
    const float* __restrict__ ln1_b, float* __restrict__ xln,
    float* __restrict__ nodes, const float* __restrict__ wek,
    const float* __restrict__ w_out, const float* __restrict__ bek,
    const float* __restrict__ b_out, float* __restrict__ W2,
    float* __restrict__ b_out2) {
  __shared__ __align__(16) float smem[8512];
  int blk = blockIdx.x;
  int tid = threadIdx.x;

  if (blk < 64) {  // ---- wfold W2 ----
    int l = blk >> 5, h = (blk >> 2) & 7, nt = blk & 3;
    float* As = smem;
    float* Bs = smem + 4160;
    const float* wekl = wek + (size_t)l * 64 * 512 + h * 64;
    const float* woutl =
        w_out + (size_t)l * 512 * 256 + (size_t)(h * 64) * 256 + nt * 64;
    for (int f = tid; f < 1024; f += 256) {
      int c = f >> 4, d4 = (f & 15) << 2;
      float4 w4 = *(const float4*)(wekl + (size_t)c * 512 + d4);
      As[c * 65 + d4 + 0] = w4.x;
      As[c * 65 + d4 + 1] = w4.y;
      As[c * 65 + d4 + 2] = w4.z;
      As[c * 65 + d4 + 3] = w4.w;
    }
    for (int f = tid; f < 1024; f += 256) {
      int d = f >> 4, n4 = (f & 15) << 2;
      float4 w4 = *(const float4*)(woutl + (size_t)d * 256 + n4);
      Bs[d * 68 + n4 + 0] = w4.x;
      Bs[d * 68 + n4 + 1] = w4.y;
      Bs[d * 68 + n4 + 2] = w4.z;
      Bs[d * 68 + n4 + 3] = w4.w;
    }
    __syncthreads();
    int tx = tid & 15, ty = tid >> 4;
    float acc[4][4] = {};
    for (int d = 0; d < 64; ++d) {
      float4 bv = *(const float4*)&Bs[d * 68 + tx * 4];
#pragma unroll
      for (int u = 0; u < 4; ++u) {
        float a = As[(ty * 4 + u) * 65 + d];
        acc[u][0] += a * bv.x;
        acc[u][1] += a * bv.y;
        acc[u][2] += a * bv.z;
        acc[u][3] += a * bv.w;
      }
    }
#pragma unroll
    for (int u = 0; u < 4; ++u) {
      float4 o = {acc[u][0], acc[u][1], acc[u][2], acc[u][3]};
      *(float4*)(W2 + (size_t)l * 512 * 256 +
                 (size_t)(h * 64 + ty * 4 + u) * 256 + nt * 64 + tx * 4) = o;
    }
  } else if (blk < 72) {  // ---- wfold b_out2 ----
    int t = blk - 64;
    int l = t >> 2, nt = t & 3;
    float* part = smem;
    int nn = tid & 63, kq = tid >> 6;
    const float* wcol = w_out + (size_t)l * 512 * 256 + nt * 64 + nn;
    float acc = 0.f;
    for (int k = kq * 128; k < kq * 128 + 128; ++k)
      acc += bek[l * 512 + k] * wcol[(size_t)k * 256];
    part[tid] = acc;
    __syncthreads();
    if (tid < 64)
      b_out2[l * 256 + nt * 64 + nn] =
          b_out[l * 256 + nt * 64 + nn] + part[nn] + part[64 + nn] +
          part[128 + nn] + part[192 + nn];
  } else if (blk < 584) {  // ---- edge LN ----
    float* ets = smem;  // 128*65
    int eidx = blk - 72;
    int i = eidx & 127, b = eidx >> 7;
    int j = tid & 127;
    bool act = tid < 128;
    if (act) {
      const float* src = edges + (size_t)b * EDGEn * Nn * Nn + i * Nn + j;
      float vals[EDGEn];
      float s = 0.f;
#pragma unroll
      for (int c = 0; c < EDGEn; ++c) {
        float x = src[(size_t)c * (Nn * Nn)];
        vals[c] = x;
        s += x;
      }
      float m = s * (1.0f / 64.0f);
      float s2 = 0.f;
#pragma unroll
      for (int c = 0; c < EDGEn; ++c) {
        float d = vals[c] - m;
        s2 += d * d;
      }
      float inv = 1.f / sqrtf(s2 * (1.0f / 64.0f) + 1e-5f);
      float* dst = e + ((size_t)(b * Nn + i) * EDGEn) * Nn + j;
#pragma unroll
      for (int c = 0; c < EDGEn; ++c) {
        float o = (vals[c] - m) * inv * eg[c] + ebb[c];
        dst[(size_t)c * Nn] = o;
        ets[j * 65 + c] = o;
      }
    }
    __syncthreads();
    if (act) {
      float* dstT = eT + ((size_t)(b * Nn + i) * Nn) * EDGEn;
#pragma unroll
      for (int it = 0; it < 16; ++it) {
        int f4 = it * 128 + j;
        int jj = f4 >> 4, c4 = (f4 & 15) << 2;
        float4 o4 = {ets[jj * 65 + c4], ets[jj * 65 + c4 + 1],
                     ets[jj * 65 + c4 + 2], ets[jj * 65 + c4 + 3]};
        *(float4*)(dstT + (size_t)jj * EDGEn + c4) = o4;
      }
    }
  } else if (blk < 600) {  // ---- rope tables ----
    int t = (blk - 584) * 256 + tid;
    if (t < Nn * 32) {
      int n = t >> 5, p = t & 31;
      float inv = powf(10000.f, -(float)(2 * p) / 64.f);
      float fr = (float)n * inv;
      cost[t] = cosf(fr);
      sint[t] = sinf(fr);
    }
  } else {  // ---- LN0 + nodes copy ----
    float* red = smem;
    int row = blk - 600;
    float v = nodes_in[(size_t)row * DIMn + tid];
    nodes[(size_t)row * DIMn + tid] = v;
    float m = block_reduce_sum_256(v, red) * (1.0f / 256.0f);
    float d = v - m;
    float var = block_reduce_sum_256(d * d, red) * (1.0f / 256.0f);
    float inv = 1.f / sqrtf(var + 1e-5f);
    xln[(size_t)row * DIMn + tid] = d * inv * ln1_g[tid] + ln1_b[tid];
  }
}

// ---------------------------------------------------------------------------
// fp32 GEMM, 32x64 tile, BK=32, 2x4 microtile, register double-buffered.
// A-stage sums `aparts` partial buffers (stride astride); aact==1: gelu after.
// Dual-N (W2n at col>=N1), dual-K (k>=Ksplit reads Wkb), split-K via z.
// act: 0 none, 1 exact gelu, 4 qkv mode (rope cols<1024; k section -> kT).
__global__ __launch_bounds__(256) void gemm_kernel(
    const float* __restrict__ A, int aparts, size_t astride, int aact,
    const float* __restrict__ W1, int N1, const float* __restrict__ b1,
    const float* __restrict__ W2n, int N2, const float* __restrict__ b2,
    const float* __restrict__ Wkb, int Ksplit, float* __restrict__ C, int M,
    int Ntot, int K, int kspan, int act, const float* __restrict__ cost,
    const float* __restrict__ sint, float* __restrict__ kT) {
  __shared__ float As[32][34];
  __shared__ __align__(16) float Bs[32][68];
  int tid = threadIdx.x;
  int bx = blockIdx.x, by = blockIdx.y, zid = blockIdx.z;
  int tx = tid & 15, ty = tid >> 4;
  int arow = tid >> 3, acol = (tid & 7) << 2;
  int brow = tid >> 4, bcol = (tid & 15) << 2;
  int col0 = bx * 64;
  const float* W = W1;
  const float* bias = b1;
  int Nw = N1, wcol = col0;
  if (W2n && col0 >= N1) {
    W = W2n;
    bias = b2;
    Nw = N2;
    wcol = col0 - N1;
  }
  int kb = zid * kspan, kend = kb + kspan;
  const float* arp = A + (size_t)(by * 32 + arow) * K;

  auto load_a = [&](int kpos) -> float4 {
    float4 a = *(const float4*)(arp + kpos + acol);
    for (int p = 1; p < aparts; ++p) {
      float4 t4 = *(const float4*)(arp + kpos + acol + (size_t)p * astride);
      a.x += t4.x;
      a.y += t4.y;
      a.z += t4.z;
      a.w += t4.w;
    }
    if (aact == 1) {
      a.x = gelu_exact(a.x);
      a.y = gelu_exact(a.y);
      a.z = gelu_exact(a.z);
      a.w = gelu_exact(a.w);
    }
    return a;
  };

  float4 a_nxt = load_a(kb);
  const float* w0p;
  const float* w1p;
  {
    int kr0 = kb + brow, kr1 = kb + brow + 16;
    w0p = (Ksplit && kr0 >= Ksplit)
              ? Wkb + (size_t)(kr0 - Ksplit) * Nw + wcol + bcol
              : W + (size_t)kr0 * Nw + wcol + bcol;
    w1p = (Ksplit && kr1 >= Ksplit)
              ? Wkb + (size_t)(kr1 - Ksplit) * Nw + wcol + bcol
              : W + (size_t)kr1 * Nw + wcol + bcol;
  }
  float4 b0_nxt = *(const float4*)w0p;
  float4 b1_nxt = *(const float4*)w1p;

  float acc[2][4] = {};
  for (int k0 = kb; k0 < kend; k0 += 32) {
    As[acol + 0][arow] = a_nxt.x;
    As[acol + 1][arow] = a_nxt.y;
    As[acol + 2][arow] = a_nxt.z;
    As[acol + 3][arow] = a_nxt.w;
    *(float4*)&Bs[brow][bcol] = b0_nxt;
    *(float4*)&Bs[brow + 16][bcol] = b1_nxt;
    __syncthreads();
    int kn = k0 + 32;
    if (kn < kend) {
      a_nxt = load_a(kn);
      int kr0 = kn + brow, kr1 = kn + brow + 16;
      w0p = (Ksplit && kr0 >= Ksplit)
                ? Wkb + (size_t)(kr0 - Ksplit) * Nw + wcol + bcol
                : W + (size_t)kr0 * Nw + wcol + bcol;
      w1p = (Ksplit && kr1 >= Ksplit)
                ? Wkb + (size_t)(kr1 - Ksplit) * Nw + wcol + bcol
                : W + (size_t)kr1 * Nw + wcol + bcol;
      b0_nxt = *(const float4*)w0p;
      b1_nxt = *(const float4*)w1p;
    }
#pragma unroll
    for (int kk = 0; kk < 32; ++kk) {
      float2 av = *(const float2*)&As[kk][ty * 2];
      float4 bv = *(const float4*)&Bs[kk][tx * 4];
      acc[0][0] += av.x * bv.x;
      acc[0][1] += av.x * bv.y;
      acc[0][2] += av.x * bv.z;
      acc[0][3] += av.x * bv.w;
      acc[1][0] += av.y * bv.x;
      acc[1][1] += av.y * bv.y;
      acc[1][2] += av.y * bv.z;
      acc[1][3] += av.y * bv.w;
    }
    __syncthreads();
  }
  int ccol = wcol + tx * 4;
  bool ksec = (act == 4) && (col0 >= 512) && (col0 < 1024);
  float* trans = (float*)Bs;
  float* Cz = C + (size_t)zid * M * Ntot;
#pragma unroll
  for (int u = 0; u < 2; ++u) {
    int r = by * 32 + ty * 2 + u;
    float o[4];
#pragma unroll
    for (int w = 0; w < 4; ++w)
      o[w] = acc[u][w] + (zid == 0 ? bias[ccol + w] : 0.f);
    if (act == 1) {
#pragma unroll
      for (int w = 0; w < 4; ++w) o[w] = gelu_exact(o[w]);
    } else if (act == 4 && col0 < 1024) {
      int n = r & 127;
      int p0 = (ccol & 63) >> 1;
      float c0 = cost[n * 32 + p0], s0 = sint[n * 32 + p0];
      float c1 = cost[n * 32 + p0 + 1], s1 = sint[n * 32 + p0 + 1];
      float x0 = o[0], x1 = o[1], x2 = o[2], x3 = o[3];
      o[0] = x0 * c0 - x1 * s0;
      o[1] = x1 * c0 + x0 * s0;
      o[2] = x2 * c1 - x3 * s1;
      o[3] = x3 * c1 + x2 * s1;
    }
    if (ksec) {
      int jl = ty * 2 + u;
#pragma unroll
      for (int w = 0; w < 4; ++w) trans[(tx * 4 + w) * 33 + jl] = o[w];
    } else {
      float4 o4 = {o[0], o[1], o[2], o[3]};
      *(float4*)(Cz + (size_t)r * Ntot + col0 + tx * 4) = o4;
    }
  }
  if (ksec) {
    __syncthreads();
    int h = (col0 - 512) >> 6;
    int bb = (by * 32) >> 7;
#pragma unroll
    for (int q = 0; q < 2; ++q) {
      int f4 = tid * 2 + q;
      int dl = f4 >> 3, j4 = (f4 & 7) << 2;
      int jj = (by * 32 + j4) & 127;
      float4 o4 = {trans[dl * 33 + j4], trans[dl * 33 + j4 + 1],
                   trans[dl * 33 + j4 + 2], trans[dl * 33 + j4 + 3]};
      *(float4*)(kT + ((size_t)(bb * 8 + h) * 64 + dl) * 128 + jj) = o4;
    }
  }
}

// ---------------------------------------------------------------------------
// dev_attn: one (b,h,iq) attention unit, t in [0,128), sm = 6208 floats.
// Identical math to R8's attn_kernel body.
DEV void dev_attn(int blk, int t, float* sm, const float* __restrict__ qkv,
                  const float* __restrict__ e, const float* __restrict__ eT,
                  const float* __restrict__ kT, const float* __restrict__ wek,
                  const float* __restrict__ w_out, const float* __restrict__ W2,
                  float* __restrict__ proj) {
  float* qs = sm;
  float* qes = sm + 256;
  float* att = sm + 512;
  float* avh = sm + 1024;
  float* aeh = sm + 1536;
  float* wekh = sm + 2048;  // 64*65
  int iq = blk & 31;
  int bh = blk >> 5;
  int h = bh & 7, b = bh >> 3;
  int i0 = iq * 4;
  int row0 = b * 128 + i0;

  for (int f = t; f < 256; f += 128) {
    int ii = f >> 6, d = f & 63;
    qs[f] = qkv[(size_t)(row0 + ii) * QKVW + h * 64 + d];
  }
  for (int f = t; f < 4096; f += 128) {
    int c = f >> 6, d = f & 63;
    wekh[c * 65 + d] = wek[(size_t)c * INNERn + h * 64 + d];
  }
  __syncthreads();

  for (int f = t; f < 256; f += 128) {
    int ii = f >> 6, c = f & 63;
    float acc = 0.f;
#pragma unroll
    for (int d = 0; d < 64; ++d) acc += qs[ii * 64 + d] * wekh[c * 65 + d];
    qes[f] = acc;
  }
  __syncthreads();

  int i2 = t >> 5, j4 = t & 31;
  float s0 = 0.f, s1 = 0.f, s2 = 0.f, s3 = 0.f;
  {
    const float* ktb = kT + ((size_t)bh * 64) * 128 + j4 * 4;
#pragma unroll
    for (int d4 = 0; d4 < 64; d4 += 4) {
      float4 q4 = *(const float4*)(qs + i2 * 64 + d4);
      float4 k0 = *(const float4*)(ktb + (size_t)(d4 + 0) * 128);
      float4 k1 = *(const float4*)(ktb + (size_t)(d4 + 1) * 128);
      float4 k2 = *(const float4*)(ktb + (size_t)(d4 + 2) * 128);
      float4 k3 = *(const float4*)(ktb + (size_t)(d4 + 3) * 128);
      s0 += q4.x * k0.x + q4.y * k1.x + q4.z * k2.x + q4.w * k3.x;
      s1 += q4.x * k0.y + q4.y * k1.y + q4.z * k2.y + q4.w * k3.y;
      s2 += q4.x * k0.z + q4.y * k1.z + q4.z * k2.z + q4.w * k3.z;
      s3 += q4.x * k0.w + q4.y * k1.w + q4.z * k2.w + q4.w * k3.w;
    }
    const float* eb = e + ((size_t)(row0 + i2) * 64) * 128 + j4 * 4;
#pragma unroll
    for (int c4 = 0; c4 < 64; c4 += 4) {
      float4 qe4 = *(const float4*)(qes + i2 * 64 + c4);
      float4 e0 = *(const float4*)(eb + (size_t)(c4 + 0) * 128);
      float4 e1 = *(const float4*)(eb + (size_t)(c4 + 1) * 128);
      float4 e2 = *(const float4*)(eb + (size_t)(c4 + 2) * 128);
      float4 e3 = *(const float4*)(eb + (size_t)(c4 + 3) * 128);
      s0 += qe4.x * e0.x + qe4.y * e1.x + qe4.z * e2.x + qe4.w * e3.x;
      s1 += qe4.x * e0.y + qe4.y * e1.y + qe4.z * e2.y + qe4.w * e3.y;
      s2 += qe4.x * e0.z + qe4.y * e1.z + qe4.z * e2.z + qe4.w * e3.z;
      s3 += qe4.x * e0.w + qe4.y * e1.w + qe4.z * e2.w + qe4.w * e3.w;
    }
    s0 *= 0.125f;
    s1 *= 0.125f;
    s2 *= 0.125f;
    s3 *= 0.125f;
  }
  {
    float mx = fmaxf(fmaxf(s0, s1), fmaxf(s2, s3));
#pragma unroll
    for (int m = 16; m >= 1; m >>= 1) mx = fmaxf(mx, __shfl_xor(mx, m));
    float p0 = expf(s0 - mx), p1 = expf(s1 - mx), p2 = expf(s2 - mx),
          p3 = expf(s3 - mx);
    float sm2 = p0 + p1 + p2 + p3;
#pragma unroll
    for (int m = 16; m >= 1; m >>= 1) sm2 += __shfl_xor(sm2, m);
    float inv = 1.f / sm2;
    float4 a4 = {p0 * inv, p1 * inv, p2 * inv, p3 * inv};
    *(float4*)(att + i2 * 128 + j4 * 4) = a4;
  }
  __syncthreads();

  {
    int d = t & 63, half = t >> 6;
    float av0 = 0.f, av1 = 0.f, av2 = 0.f, av3 = 0.f;
    float ae0 = 0.f, ae1 = 0.f, ae2 = 0.f, ae3 = 0.f;
    const float* vb = qkv + (size_t)(b * 128) * QKVW + 1024 + h * 64 + d;
    const float* etb = eT + ((size_t)row0 * 128) * 64 + d;
    for (int jq = 0; jq < 16; ++jq) {
      int jb = half * 64 + jq * 4;
      float4 a0 = *(const float4*)(att + 0 * 128 + jb);
      float4 a1 = *(const float4*)(att + 1 * 128 + jb);
      float4 a2 = *(const float4*)(att + 2 * 128 + jb);
      float4 a3 = *(const float4*)(att + 3 * 128 + jb);
#pragma unroll
      for (int tt = 0; tt < 4; ++tt) {
        int j = jb + tt;
        float vv = vb[(size_t)j * QKVW];
        float at0 = ((const float*)&a0)[tt];
        float at1 = ((const float*)&a1)[tt];
        float at2 = ((const float*)&a2)[tt];
        float at3 = ((const float*)&a3)[tt];
        av0 += at0 * vv;
        av1 += at1 * vv;
        av2 += at2 * vv;
        av3 += at3 * vv;
        float e0 = etb[(size_t)j * 64];
        float e1 = etb[8192 + (size_t)j * 64];
        float e2 = etb[16384 + (size_t)j * 64];
        float e3 = etb[24576 + (size_t)j * 64];
        ae0 += at0 * e0;
        ae1 += at1 * e1;
        ae2 += at2 * e2;
        ae3 += at3 * e3;
      }
    }
    avh[half * 256 + 0 * 64 + d] = av0;
    avh[half * 256 + 1 * 64 + d] = av1;
    avh[half * 256 + 2 * 64 + d] = av2;
    avh[half * 256 + 3 * 64 + d] = av3;
    aeh[half * 256 + 0 * 64 + d] = ae0;
    aeh[half * 256 + 1 * 64 + d] = ae1;
    aeh[half * 256 + 2 * 64 + d] = ae2;
    aeh[half * 256 + 3 * 64 + d] = ae3;
  }
  __syncthreads();

  for (int f = t; f < 256; f += 128) {
    int ii = f >> 6, dd = f & 63;
    att[ii * 128 + dd] = avh[ii * 64 + dd] + avh[256 + ii * 64 + dd];
    att[ii * 128 + 64 + dd] = aeh[ii * 64 + dd] + aeh[256 + ii * 64 + dd];
  }
  __syncthreads();

  {
    int rp = t >> 6, n4 = (t & 63) << 2;
    int r0 = rp * 2, r1 = rp * 2 + 1;
    float o0[4] = {}, o1[4] = {};
    const float* wo = w_out + (size_t)(h * 64) * 256 + n4;
#pragma unroll 8
    for (int k = 0; k < 64; ++k) {
      float4 w4 = *(const float4*)(wo + (size_t)k * 256);
      float a0 = att[r0 * 128 + k];
      float a1 = att[r1 * 128 + k];
      o0[0] += a0 * w4.x;
      o0[1] += a0 * w4.y;
      o0[2] += a0 * w4.z;
      o0[3] += a0 * w4.w;
      o1[0] += a1 * w4.x;
      o1[1] += a1 * w4.y;
      o1[2] += a1 * w4.z;
      o1[3] += a1 * w4.w;
    }
    const float* w2 = W2 + (size_t)(h * 64) * 256 + n4;
#pragma unroll 8
    for (int k = 0; k < 64; ++k) {
      float4 w4 = *(const float4*)(w2 + (size_t)k * 256);
      float a0 = att[r0 * 128 + 64 + k];
      float a1 = att[r1 * 128 + 64 + k];
      o0[0] += a0 * w4.x;
      o0[1] += a0 * w4.y;
      o0[2] += a0 * w4.z;
      o0[3] += a0 * w4.w;
      o1[0] += a1 * w4.x;
      o1[1] += a1 * w4.y;
      o1[2] += a1 * w4.z;
      o1[3] += a1 * w4.w;
    }
    float* pp = proj + (size_t)h * PART;
    float4 v0 = {o0[0], o0[1], o0[2], o0[3]};
    float4 v1 = {o1[0], o1[1], o1[2], o1[3]};
    *(float4*)(pp + (size_t)(row0 + r0) * 256 + n4) = v0;
    *(float4*)(pp + (size_t)(row0 + r1) * 256 + n4) = v1;
  }
}

// ---------------------------------------------------------------------------
// attn_kernel: 512 blocks x 256 threads. Two units per block in thread
// halves, paired as (b, 2hp, iq) + (b, 2hp+1, iq): same (b,iq) -> the halves
// issue IDENTICAL e/eT addresses -> L1/L2 coalescing halves e-traffic.
__global__ __launch_bounds__(256) void attn_kernel(
    const float* __restrict__ qkv, const float* __restrict__ e,
    const float* __restrict__ eT, const float* __restrict__ kT,
    const float* __restrict__ wek, const float* __restrict__ w_out,
    const float* __restrict__ W2, float* __restrict__ proj) {
  __shared__ __align__(16) float smem[2][6208];
  int half = threadIdx.x >> 7;
  int t = threadIdx.x & 127;
  int bx = blockIdx.x;  // (b*4 + hp)*32 + iq
  int iq = bx & 31;
  int hp = (bx >> 5) & 3;
  int b = bx >> 7;
  int h = hp * 2 + half;
  int blk = ((b * 8 + h) * 32) + iq;
  dev_attn(blk, t, smem[half], qkv, e, eT, kT, wek, w_out, W2, proj);
}

// ---------------------------------------------------------------------------
// Gated residual + optional fused LN. x = sum of nparts partials (+ badd).
__global__ __launch_bounds__(256) void gate_ln_kernel(
    const float* __restrict__ x, int nparts, const float* __restrict__ badd,
    float* __restrict__ nodes, const float* __restrict__ gw,
    const float* __restrict__ lng, const float* __restrict__ lnb,
    float* __restrict__ xln) {
  __shared__ float red[4];
  int row = blockIdx.x, tid = threadIdx.x;
  size_t off = (size_t)row * DIMn + tid;
  float xv = x[off];
  for (int p = 1; p < nparts; ++p) xv += x[off + (size_t)p * PART];
  if (badd) xv += badd[tid];
  float rv = nodes[off];
  float pv =
      xv * gw[tid] + rv * gw[DIMn + tid] + (xv - rv) * gw[2 * DIMn + tid];
  float ssum = block_reduce_sum_256(pv, red);
  float gsig = 1.f / (1.f + expf(-ssum));
  float nv = xv * gsig + rv * (1.f - gsig);
  nodes[off] = nv;
  if (lng) {
    float m = block_reduce_sum_256(nv, red) * (1.0f / 256.0f);
    float d = nv - m;
    float var = block_reduce_sum_256(d * d, red) * (1.0f / 256.0f);
    float inv = 1.f / sqrtf(var + 1e-5f);
    xln[off] = d * inv * lng[tid] + lnb[tid];
  }
}

// ---------------------------------------------------------------------------
// VQ nearest neighbor: thread-per-codebook-entry, 4 rows per block.
__global__ __launch_bounds__(256) void vq_kernel(
    const float* __restrict__ nodes, const float* __restrict__ codebook,
    float* __restrict__ out) {
  __shared__ __align__(16) float zs[4 * 256];
  __shared__ float wval[4][4];
  __shared__ int widx[4][4];
  __shared__ int fidx[4];
  int row0 = blockIdx.x * 4;
  int tid = threadIdx.x;
  for (int f = tid; f < 1024; f += 256) zs[f] = nodes[(size_t)row0 * DIMn + f];
  __syncthreads();
  int k1 = tid, k2 = tid + 256;
  const float4* c1p = (const float4*)(codebook + (size_t)k1 * DIMn);
  const float4* c2p = (const float4*)(codebook + (size_t)k2 * DIMn);
  float dot[4][2] = {};
  float cc0 = 0.f, cc1 = 0.f;
#pragma unroll 8
  for (int d4 = 0; d4 < 64; ++d4) {
    float4 c1 = c1p[d4], c2 = c2p[d4];
    cc0 += c1.x * c1.x + c1.y * c1.y + c1.z * c1.z + c1.w * c1.w;
    cc1 += c2.x * c2.x + c2.y * c2.y + c2.z * c2.z + c2.w * c2.w;
#pragma unroll
    for (int r = 0; r < 4; ++r) {
      float4 z = *(const float4*)&zs[r * 256 + d4 * 4];
      dot[r][0] += c1.x * z.x + c1.y * z.y + c1.z * z.z + c1.w * z.w;
      dot[r][1] += c2.x * z.x + c2.y * z.y + c2.z * z.z + c2.w * z.w;
    }
  }
  int lane = tid & 63, w = tid >> 6;
#pragma unroll
  for (int r = 0; r < 4; ++r) {
    float bv = cc0 - 2.f * dot[r][0];
    int bi = k1;
    float v2 = cc1 - 2.f * dot[r][1];
    if (v2 < bv) {
      bv = v2;
      bi = k2;
    }
#pragma unroll
    for (int m = 32; m >= 1; m >>= 1) {
      float ov = __shfl_xor(bv, m);
      int oi = __shfl_xor(bi, m);
      if (ov < bv || (ov == bv && oi < bi)) {
        bv = ov;
        bi = oi;
      }
    }
    if (lane == 0) {
      wval[r][w] = bv;
      widx[r][w] = bi;
    }
  }
  __syncthreads();
  if (tid < 4) {
    float bb = wval[tid][0];
    int bi = widx[tid][0];
    for (int t = 1; t < 4; ++t)
      if (wval[tid][t] < bb || (wval[tid][t] == bb && widx[tid][t] < bi)) {
        bb = wval[tid][t];
        bi = widx[tid][t];
      }
    fidx[tid] = bi;
  }
  __syncthreads();
  for (int f = tid; f < 1024; f += 256) {
    int r = f >> 8, d = f & 255;
    float zv = zs[f];
    float zq = codebook[(size_t)fidx[r] * DIMn + d];
    out[(size_t)(row0 + r) * DIMn + d] = zv + (zq - zv);
  }
}

// ---------------------------------------------------------------------------
extern "C" void kernel_launch(void* const* d_in, const int* in_sizes, int n_in,
                              void* d_out, int out_size, void* d_ws,
                              size_t ws_size, hipStream_t stream) {
  const float* nodes_in = (const float*)d_in[0];
  const float* edges = (const float*)d_in[1];
  const float* edge_ln_g = (const float*)d_in[2];
  const float* edge_ln_b = (const float*)d_in[3];
  const float* ln1_g = (const float*)d_in[4];
  const float* ln1_b = (const float*)d_in[5];
  const float* w_exp = (const float*)d_in[6];
  const float* b_exp = (const float*)d_in[7];
  const float* w_q = (const float*)d_in[8];
  const float* b_q = (const float*)d_in[9];
  const float* w_kv = (const float*)d_in[10];
  const float* b_kv = (const float*)d_in[11];
  const float* w_ekv = (const float*)d_in[12];
  const float* b_ekv = (const float*)d_in[13];
  const float* w_out = (const float*)d_in[14];
  const float* b_out = (const float*)d_in[15];
  const float* gate1_w = (const float*)d_in[16];
  const float* ln2_g = (const float*)d_in[17];
  const float* ln2_b = (const float*)d_in[18];
  const float* w_ff1 = (const float*)d_in[19];
  const float* b_ff1 = (const float*)d_in[20];
  const float* w_ff2 = (const float*)d_in[21];
  const float* b_ff2 = (const float*)d_in[22];
  const float* gate2_w = (const float*)d_in[23];
  const float* codebook = (const float*)d_in[24];

  float* ws = (float*)d_ws;
  float* e_buf = ws;                  // 4194304
  float* eT_buf = e_buf + 4194304;    // 4194304
  float* cost = eT_buf + 4194304;     // 4096
  float* sint = cost + 4096;          // 4096
  float* nodes = sint + 4096;         // 131072
  float* xln = nodes + 131072;        // 131072
  float* xe = xln + 131072;           // 1048576 (4 split-K partials)
  float* qkvb = xe + 1048576;         // 786432
  float* kTb = qkvb + 786432;         // 262144
  float* proj = kTb + 262144;         // 1048576 (8 per-head / 8 splitK parts)
  float* ff1 = proj + 1048576;        // 2097152 (4 split-K partials)
  float* W2buf = ff1 + 2097152;       // 262144
  float* bout2 = W2buf + 262144;      // 512

  // one-shot setup: wfold + edge LN + rope tables + LN0 (+nodes copy)
  prep_kernel<<<1112, 256, 0, stream>>>(
      edges, edge_ln_g, edge_ln_b, e_buf, eT_buf, cost, sint, nodes_in, ln1_g,
      ln1_b, xln, nodes, w_ekv, w_out, b_ekv, b_out, W2buf, bout2);

  for (int l = 0; l < DEPTHn; ++l) {
    // exp: split-K x4 -> xe partials (stride 262144)
    gemm_kernel<<<dim3(8, 16, 4), 256, 0, stream>>>(
        xln, 1, 0, 0, w_exp + l * 256 * 512, 512, b_exp + l * 512, nullptr, 0,
        nullptr, nullptr, 0, xe, 512, 512, 256, 64, 0, cost, sint, nullptr);
    // fused q|kv (A = sum of 4 xe partials), rope epilogue + kT scatter
    gemm_kernel<<<dim3(24, 16, 1), 256, 0, stream>>>(
        xe, 4, 262144, 0, w_q + l * 512 * 512, 512, b_q + l * 512,
        w_kv + l * 512 * 1024, 1024, b_kv + l * 1024, nullptr, 0, qkvb, 512,
        QKVW, 512, 512, 4, cost, sint, kTb);
    // attention (+qe, +out-proj per-head partials); head-paired blocks
    attn_kernel<<<512, 256, 0, stream>>>(qkvb, e_buf, eT_buf, kTb,
                                         w_ekv + l * 64 * 512,
                                         w_out + l * 512 * 256,
                                         W2buf + l * 512 * 256, proj);
    gate_ln_kernel<<<512, 256, 0, stream>>>(
        proj, 8, bout2 + l * 256, nodes, gate1_w + l * 768, ln2_g + l * 256,
        ln2_b + l * 256, xln);
    // ff1: split-K x4 (gelu deferred to ff2 A-stage), partial stride 524288
    gemm_kernel<<<dim3(16, 16, 4), 256, 0, stream>>>(
        xln, 1, 0, 0, w_ff1 + l * 256 * 1024, 1024, b_ff1 + l * 1024, nullptr,
        0, nullptr, nullptr, 0, ff1, 512, 1024, 256, 64, 0, cost, sint,
        nullptr);
    // ff2: A = gelu(sum of 4 ff1 partials), split-K x8 -> proj partials
    gemm_kernel<<<dim3(4, 16, 8), 256, 0, stream>>>(
        ff1, 4, 524288, 1, w_ff2 + l * 1024 * 256, 256, b_ff2 + l * 256,
        nullptr, 0, nullptr, nullptr, 0, proj, 512, 256, 1024, 128, 0, cost,
        sint, nullptr);
    const float* nlng = (l + 1 < DEPTHn) ? ln1_g + (l + 1) * 256 : nullptr;
    const float* nlnb = (l + 1 < DEPTHn) ? ln1_b + (l + 1) * 256 : nullptr;
    gate_ln_kernel<<<512, 256, 0, stream>>>(proj, 8, nullptr, nodes,
                                            gate2_w + l * 768, nlng, nlnb,
                                            xln);
  }
  vq_kernel<<<128, 256, 0, stream>>>(nodes, codebook, (float*)d_out);
}